// Round 12
// baseline (374.572 us; speedup 1.0000x reference)
//
#include <hip/hip_runtime.h>
#include <hip/hip_bf16.h>
#include <cstdint>
#include <cmath>

// ---------------------------------------------------------------------------
// VGAE-style GCN forward, CSR-gather formulation:
//   deg(int) -> 3-phase parallel scan (fused dis + cursor init) -> CSR fill(nt) ->
//   wT = bf16(W1^T), w4T = bf16(W4^T)  (one-time, L2-resident)
//   gemm1 (MFMA bf16): Abf = bf16((x@W1)*dis), B = (x@W1)*dis^2
//   gather<RELU>: h=relu(B + dis*sum Abf[src] + b1); Abf=bf16(h*dis), B=h*dis^2
//   gather<PLAIN>: B = hagg (f32), Bbf = bf16(hagg)
//   pool2_mfma: T = noise*exp(Bbf@W4^T+b4) via MFMA, segment-sum by sorted batch
//   poolH: block-per-graph coalesced f32 column sums of hagg
//   final: counts via binary search + pooled mean algebra + FC + log_softmax
// ---------------------------------------------------------------------------

typedef __attribute__((ext_vector_type(8))) short bf16x8;
typedef __attribute__((ext_vector_type(4))) float f32x4;

__device__ __forceinline__ unsigned short f2bf(float f) {
    union { float f; unsigned u; } v; v.f = f;
    unsigned u = v.u;
    return (unsigned short)((u + 0x7fffu + ((u >> 16) & 1u)) >> 16);   // RNE
}
__device__ __forceinline__ float bf2f(unsigned b) {
    union { float f; unsigned u; } v; v.u = b << 16; return v.f;
}
__device__ __forceinline__ unsigned packbf(float lo, float hi) {
    return (unsigned)f2bf(lo) | ((unsigned)f2bf(hi) << 16);
}

__global__ __launch_bounds__(256) void deg_kernel(const int* __restrict__ dst,
                                                  int* __restrict__ deg, int E) {
    int e = blockIdx.x * 256 + threadIdx.x;
    if (e < E) atomicAdd(&deg[dst[e]], 1);
}

// --- 3-phase scan: 1024 elements per block (4 per thread) ---
__global__ __launch_bounds__(256) void scan1_kernel(const int* __restrict__ deg,
                                                    int* __restrict__ bsum, int N) {
    int t = threadIdx.x;
    int base = blockIdx.x * 1024 + t * 4;
    int s = 0;
    if (base + 3 < N) {
        int4 v = *(const int4*)(deg + base);
        s = v.x + v.y + v.z + v.w;
    } else {
        for (int i = 0; i < 4; i++) if (base + i < N) s += deg[base + i];
    }
    __shared__ int red[256];
    red[t] = s;
    __syncthreads();
    for (int off = 128; off > 0; off >>= 1) {
        if (t < off) red[t] += red[t + off];
        __syncthreads();
    }
    if (t == 0) bsum[blockIdx.x] = red[0];
}

__global__ __launch_bounds__(256) void scan2_kernel(int* __restrict__ bsum, int nb) {
    __shared__ int s[256];
    int t = threadIdx.x;
    s[t] = (t < nb) ? bsum[t] : 0;
    __syncthreads();
    for (int off = 1; off < 256; off <<= 1) {
        int u = (t >= off) ? s[t - off] : 0;
        __syncthreads();
        s[t] += u;
        __syncthreads();
    }
    if (t < nb) bsum[t] = (t == 0) ? 0 : s[t - 1];
}

// write offs (exclusive scan), cursor (= offs), dis = rsqrt(deg+1); offs[N] = E
__global__ __launch_bounds__(256) void scan3_kernel(const int* __restrict__ deg,
                                                    const int* __restrict__ bsum,
                                                    int* __restrict__ offs,
                                                    int* __restrict__ cursor,
                                                    float* __restrict__ dis,
                                                    int N, int E) {
    int t = threadIdx.x;
    int bid = blockIdx.x;
    int base = bid * 1024 + t * 4;
    int d[4] = {0, 0, 0, 0};
    if (base + 3 < N) {
        int4 v = *(const int4*)(deg + base);
        d[0] = v.x; d[1] = v.y; d[2] = v.z; d[3] = v.w;
    } else {
        for (int i = 0; i < 4; i++) if (base + i < N) d[i] = deg[base + i];
    }
    int s = d[0] + d[1] + d[2] + d[3];
    __shared__ int red[256];
    red[t] = s;
    __syncthreads();
    for (int off = 1; off < 256; off <<= 1) {
        int u = (t >= off) ? red[t - off] : 0;
        __syncthreads();
        red[t] += u;
        __syncthreads();
    }
    int run = bsum[bid] + ((t == 0) ? 0 : red[t - 1]);
#pragma unroll
    for (int i = 0; i < 4; i++) {
        int idx = base + i;
        if (idx < N) {
            offs[idx] = run;
            cursor[idx] = run;
            dis[idx] = rsqrtf((float)d[i] + 1.0f);
            run += d[i];
        }
    }
    if (bid == 0 && t == 0) offs[N] = E;
}

// nontemporal adj stores: scattered 4B writes stream past the 8 per-XCD L2s
__global__ __launch_bounds__(256) void fill_kernel(const int* __restrict__ src,
                                                   const int* __restrict__ dst,
                                                   int* __restrict__ cursor,
                                                   int* __restrict__ adj, int E) {
    int e = blockIdx.x * 256 + threadIdx.x;
    if (e >= E) return;
    int pos = atomicAdd(&cursor[dst[e]], 1);
    __builtin_nontemporal_store(src[e], &adj[pos]);
}

// one-time: wT[c][k] = bf16(W1[k][c]); W1 is [256][128]
__global__ __launch_bounds__(256) void wt_kernel(const float* __restrict__ W,
                                                 unsigned short* __restrict__ wT) {
    int idx = blockIdx.x * 256 + threadIdx.x;   // 0..32767
    if (idx < 32768) {
        int k = idx >> 7;
        int c = idx & 127;
        wT[c * 256 + k] = f2bf(W[idx]);
    }
}

// one-time: w4T[c][k] = bf16(W4[k][c]); W4 is [128][64]
__global__ __launch_bounds__(256) void wt4_kernel(const float* __restrict__ W4,
                                                  unsigned short* __restrict__ w4T) {
    int idx = blockIdx.x * 256 + threadIdx.x;   // 0..8191
    if (idx < 8192) {
        int k = idx >> 6;
        int c = idx & 63;
        w4T[c * 128 + k] = f2bf(W4[idx]);
    }
}

// MFMA gemm1: h0 = x@W1 (M=N, Nc=128, K=256), bf16 inputs, f32 acc.
__global__ __launch_bounds__(256) void gemm1_mfma(const float* __restrict__ x,
                                                  const unsigned short* __restrict__ wT,
                                                  const float* __restrict__ dis,
                                                  unsigned short* __restrict__ Abf,
                                                  float* __restrict__ B, int N) {
    __shared__ unsigned short xs[64 * 264];   // [row][264], pad 8
    int tid = threadIdx.x;
    int rowBase = blockIdx.x * 64;
#pragma unroll
    for (int i = 0; i < 16; i++) {
        int u = tid + i * 256;
        int r = u >> 6;
        int c = u & 63;
        float4 v = make_float4(0.f, 0.f, 0.f, 0.f);
        int row = rowBase + r;
        if (row < N) v = *(const float4*)(x + (size_t)row * 256 + c * 4);
        ushort4 b;
        b.x = f2bf(v.x); b.y = f2bf(v.y); b.z = f2bf(v.z); b.w = f2bf(v.w);
        *(ushort4*)&xs[r * 264 + c * 4] = b;
    }
    __syncthreads();

    int wv = tid >> 6;
    int l = tid & 63;
    int lr = l & 15;
    int lk = l >> 4;
    int colBase = wv * 32;

    f32x4 acc[4][2];
#pragma unroll
    for (int rt = 0; rt < 4; rt++)
#pragma unroll
        for (int ct = 0; ct < 2; ct++) acc[rt][ct] = (f32x4){0.f, 0.f, 0.f, 0.f};

    for (int ks = 0; ks < 8; ks++) {
        int kbase = ks * 32 + lk * 8;
        bf16x8 a[4], b[2];
#pragma unroll
        for (int rt = 0; rt < 4; rt++)
            a[rt] = *(const bf16x8*)&xs[(rt * 16 + lr) * 264 + kbase];
#pragma unroll
        for (int ct = 0; ct < 2; ct++)
            b[ct] = *(const bf16x8*)(wT + (size_t)(colBase + ct * 16 + lr) * 256 + kbase);
#pragma unroll
        for (int rt = 0; rt < 4; rt++)
#pragma unroll
            for (int ct = 0; ct < 2; ct++)
                acc[rt][ct] = __builtin_amdgcn_mfma_f32_16x16x32_bf16(
                    a[rt], b[ct], acc[rt][ct], 0, 0, 0);
    }

#pragma unroll
    for (int rt = 0; rt < 4; rt++) {
#pragma unroll
        for (int j = 0; j < 4; j++) {
            int row = rowBase + rt * 16 + lk * 4 + j;
            if (row >= N) continue;
            float dv = dis[row];
            float d2 = dv * dv;
#pragma unroll
            for (int ct = 0; ct < 2; ct++) {
                int col = colBase + ct * 16 + lr;
                float v = acc[rt][ct][j];
                Abf[(size_t)row * 128 + col] = f2bf(v * dv);
                B[(size_t)row * 128 + col] = v * d2;
            }
        }
    }
}

// 16 lanes per node (8 bf16 feats/lane via uint4 = 16B), 16 nodes per block.
// MODE 0: B[node] += dis*a (f32) and Bbf[node] = bf16(result)
// MODE 1: v = relu(B + dis*a + b1); Aout=bf16(v*dis); B=v*dis^2
template <int MODE>
__global__ __launch_bounds__(256) void gather_kernel(const int* __restrict__ offs,
                                                     const int* __restrict__ adj,
                                                     const float* __restrict__ dis,
                                                     const float* __restrict__ b1,
                                                     const unsigned short* __restrict__ Ain,
                                                     unsigned short* __restrict__ Aout,
                                                     float* __restrict__ B,
                                                     unsigned short* __restrict__ Bbf, int N) {
    int tid = threadIdx.x;
    int lane = tid & 15;                       // feats [lane*8, lane*8+8)
    int node = blockIdx.x * 16 + (tid >> 4);
    if (node >= N) return;
    int beg = offs[node];
    int end = offs[node + 1];
    float a[8];
#pragma unroll
    for (int j = 0; j < 8; j++) a[j] = 0.f;
    int e = beg;
    for (; e + 3 < end; e += 4) {
        int s0 = adj[e], s1 = adj[e + 1], s2 = adj[e + 2], s3 = adj[e + 3];
        uint4 r0 = ((const uint4*)(Ain + (size_t)s0 * 128))[lane];
        uint4 r1 = ((const uint4*)(Ain + (size_t)s1 * 128))[lane];
        uint4 r2 = ((const uint4*)(Ain + (size_t)s2 * 128))[lane];
        uint4 r3 = ((const uint4*)(Ain + (size_t)s3 * 128))[lane];
        a[0] += bf2f(r0.x & 0xffffu) + bf2f(r1.x & 0xffffu) + bf2f(r2.x & 0xffffu) + bf2f(r3.x & 0xffffu);
        a[1] += bf2f(r0.x >> 16)     + bf2f(r1.x >> 16)     + bf2f(r2.x >> 16)     + bf2f(r3.x >> 16);
        a[2] += bf2f(r0.y & 0xffffu) + bf2f(r1.y & 0xffffu) + bf2f(r2.y & 0xffffu) + bf2f(r3.y & 0xffffu);
        a[3] += bf2f(r0.y >> 16)     + bf2f(r1.y >> 16)     + bf2f(r2.y >> 16)     + bf2f(r3.y >> 16);
        a[4] += bf2f(r0.z & 0xffffu) + bf2f(r1.z & 0xffffu) + bf2f(r2.z & 0xffffu) + bf2f(r3.z & 0xffffu);
        a[5] += bf2f(r0.z >> 16)     + bf2f(r1.z >> 16)     + bf2f(r2.z >> 16)     + bf2f(r3.z >> 16);
        a[6] += bf2f(r0.w & 0xffffu) + bf2f(r1.w & 0xffffu) + bf2f(r2.w & 0xffffu) + bf2f(r3.w & 0xffffu);
        a[7] += bf2f(r0.w >> 16)     + bf2f(r1.w >> 16)     + bf2f(r2.w >> 16)     + bf2f(r3.w >> 16);
    }
    for (; e < end; e++) {
        int s = adj[e];
        uint4 r0 = ((const uint4*)(Ain + (size_t)s * 128))[lane];
        a[0] += bf2f(r0.x & 0xffffu);
        a[1] += bf2f(r0.x >> 16);
        a[2] += bf2f(r0.y & 0xffffu);
        a[3] += bf2f(r0.y >> 16);
        a[4] += bf2f(r0.z & 0xffffu);
        a[5] += bf2f(r0.z >> 16);
        a[6] += bf2f(r0.w & 0xffffu);
        a[7] += bf2f(r0.w >> 16);
    }
    float dd = dis[node];
    float* brow = B + (size_t)node * 128 + lane * 8;
    float4 cur0 = *(float4*)brow;
    float4 cur1 = *(float4*)(brow + 4);
    if (MODE == 0) {
        cur0.x += dd * a[0]; cur0.y += dd * a[1]; cur0.z += dd * a[2]; cur0.w += dd * a[3];
        cur1.x += dd * a[4]; cur1.y += dd * a[5]; cur1.z += dd * a[6]; cur1.w += dd * a[7];
        *(float4*)brow = cur0;
        *(float4*)(brow + 4) = cur1;
        uint4 w;
        w.x = packbf(cur0.x, cur0.y);
        w.y = packbf(cur0.z, cur0.w);
        w.z = packbf(cur1.x, cur1.y);
        w.w = packbf(cur1.z, cur1.w);
        *(uint4*)(Bbf + (size_t)node * 128 + lane * 8) = w;
    } else {
        const float* b1p = b1 + lane * 8;
        float4 bb0 = *(const float4*)b1p;
        float4 bb1 = *(const float4*)(b1p + 4);
        float v0 = fmaxf(cur0.x + dd * a[0] + bb0.x, 0.f);
        float v1 = fmaxf(cur0.y + dd * a[1] + bb0.y, 0.f);
        float v2 = fmaxf(cur0.z + dd * a[2] + bb0.z, 0.f);
        float v3 = fmaxf(cur0.w + dd * a[3] + bb0.w, 0.f);
        float v4 = fmaxf(cur1.x + dd * a[4] + bb1.x, 0.f);
        float v5 = fmaxf(cur1.y + dd * a[5] + bb1.y, 0.f);
        float v6 = fmaxf(cur1.z + dd * a[6] + bb1.z, 0.f);
        float v7 = fmaxf(cur1.w + dd * a[7] + bb1.w, 0.f);
        uint4 w;
        w.x = packbf(v0 * dd, v1 * dd);
        w.y = packbf(v2 * dd, v3 * dd);
        w.z = packbf(v4 * dd, v5 * dd);
        w.w = packbf(v6 * dd, v7 * dd);
        *(uint4*)(Aout + (size_t)node * 128 + lane * 8) = w;
        float d2 = dd * dd;
        *(float4*)brow       = make_float4(v0 * d2, v1 * d2, v2 * d2, v3 * d2);
        *(float4*)(brow + 4) = make_float4(v4 * d2, v5 * d2, v6 * d2, v7 * d2);
    }
}

__device__ __forceinline__ int lbound_lds(const int* a, int n, int v) {
    int l = 0, r = n;
    while (l < r) { int m = (l + r) >> 1; if (a[m] < v) l = m + 1; else r = m; }
    return l;
}

// MFMA pool: T = noise*exp(Bbf@W4^T + b4); segment-sum T (64 cols) by sorted batch.
// 64-row tile per block; wave wv -> cols [wv*16, wv*16+16); K=128.
__global__ __launch_bounds__(256) void pool2_mfma(const unsigned short* __restrict__ Bbf,
                                                  const unsigned short* __restrict__ w4T,
                                                  const float* __restrict__ b4,
                                                  const float* __restrict__ noise,
                                                  const int* __restrict__ batch,
                                                  float* __restrict__ pooledT, int N) {
    __shared__ float Tld[64][68];
    __shared__ int sbatch[64];
    int tid = threadIdx.x;
    int rowBase = blockIdx.x * 64;
    int nrows = min(64, N - rowBase);
    if (tid < 64) sbatch[tid] = (rowBase + tid < N) ? batch[rowBase + tid] : 0x7fffffff;

    int wv = tid >> 6;
    int l = tid & 63;
    int lr = l & 15;
    int lk = l >> 4;
    int col = wv * 16 + lr;

    f32x4 acc[4];
#pragma unroll
    for (int rt = 0; rt < 4; rt++) acc[rt] = (f32x4){0.f, 0.f, 0.f, 0.f};

#pragma unroll
    for (int ks = 0; ks < 4; ks++) {
        int kbase = ks * 32 + lk * 8;
        bf16x8 b = *(const bf16x8*)(w4T + (size_t)col * 128 + kbase);
#pragma unroll
        for (int rt = 0; rt < 4; rt++) {
            int row = rowBase + rt * 16 + lr;
            bf16x8 a = {0, 0, 0, 0, 0, 0, 0, 0};
            if (row < N) a = *(const bf16x8*)(Bbf + (size_t)row * 128 + kbase);
            acc[rt] = __builtin_amdgcn_mfma_f32_16x16x32_bf16(a, b, acc[rt], 0, 0, 0);
        }
    }
    __syncthreads();   // sbatch visible; Tld about to be written

    float bv = b4[col];
#pragma unroll
    for (int rt = 0; rt < 4; rt++) {
#pragma unroll
        for (int j = 0; j < 4; j++) {
            int r = rt * 16 + lk * 4 + j;
            int row = rowBase + r;
            if (row < N)
                Tld[r][col] = noise[(size_t)row * 64 + col] * expf(acc[rt][j] + bv);
        }
    }
    __syncthreads();

    int g0 = sbatch[0];
    int g1 = (nrows > 0) ? sbatch[nrows - 1] : g0;
    for (int g = g0; g <= g1; g++) {
        int lo = lbound_lds(sbatch, nrows, g);
        int hi = lbound_lds(sbatch, nrows, g + 1);
        if (hi > lo && tid < 64) {
            float s = 0.f;
            for (int r = lo; r < hi; r++) s += Tld[r][tid];
            atomicAdd(&pooledT[g * 64 + tid], s);
        }
    }
}

// block per graph: pooledH[g][f] = sum of B rows in [lo,hi), coalesced f32.
__global__ __launch_bounds__(128) void poolH_kernel(const float* __restrict__ B,
                                                    const int* __restrict__ batch,
                                                    float* __restrict__ pooledH, int N) {
    int g = blockIdx.x;
    int f = threadIdx.x;   // 0..127
    __shared__ int seg[2];
    if (f < 2) {
        int target = g + f;
        int l = 0, r = N;
        while (l < r) { int m = (l + r) >> 1; if (batch[m] < target) l = m + 1; else r = m; }
        seg[f] = l;
    }
    __syncthreads();
    float s = 0.f;
    for (int node = seg[0]; node < seg[1]; node++)
        s += B[(size_t)node * 128 + f];
    pooledH[g * 128 + f] = s;
}

// pooled = (pooledH@W3 + cnt*b3 + pooledT)/max(cnt,1); logits -> log_softmax
__global__ __launch_bounds__(64) void final_kernel(const float* __restrict__ pooledH,
                                                   const float* __restrict__ pooledT,
                                                   const int* __restrict__ batch,
                                                   const float* __restrict__ W3,
                                                   const float* __restrict__ b3,
                                                   const float* __restrict__ Wfc,
                                                   const float* __restrict__ bfc,
                                                   float* __restrict__ out, int N) {
    int g = blockIdx.x;
    int f = threadIdx.x;
    __shared__ int seg[2];
    if (f < 2) {
        int target = g + f;
        int l = 0, r = N;
        while (l < r) { int m = (l + r) >> 1; if (batch[m] < target) l = m + 1; else r = m; }
        seg[f] = l;
    }
    __syncthreads();
    float cnt = (float)(seg[1] - seg[0]);
    float denom = fmaxf(cnt, 1.0f);
    float p = pooledT[g * 64 + f] + cnt * b3[f];
    const float* ph = pooledH + g * 128;
#pragma unroll
    for (int k = 0; k < 128; k++) p = fmaf(ph[k], W3[k * 64 + f], p);
    p /= denom;
    __shared__ float pl[64];
    __shared__ float lg[4];
    pl[f] = p;
    __syncthreads();
    if (f < 4) {
        float l = bfc[f];
#pragma unroll
        for (int k = 0; k < 64; k++) l = fmaf(pl[k], Wfc[k * 4 + f], l);
        lg[f] = l;
    }
    __syncthreads();
    if (f == 0) {
        float m = fmaxf(fmaxf(lg[0], lg[1]), fmaxf(lg[2], lg[3]));
        float s = expf(lg[0] - m) + expf(lg[1] - m) + expf(lg[2] - m) + expf(lg[3] - m);
        float lse = logf(s);
#pragma unroll
        for (int j = 0; j < 4; j++) out[g * 4 + j] = lg[j] - m - lse;
    }
}

extern "C" void kernel_launch(void* const* d_in, const int* in_sizes, int n_in,
                              void* d_out, int out_size, void* d_ws, size_t ws_size,
                              hipStream_t stream) {
    const float* x     = (const float*)d_in[0];
    const int*   ei    = (const int*)d_in[1];
    const int*   batch = (const int*)d_in[2];
    const float* W1    = (const float*)d_in[3];
    const float* b1    = (const float*)d_in[4];
    const float* W3    = (const float*)d_in[5];
    const float* b3    = (const float*)d_in[6];
    const float* W4    = (const float*)d_in[7];
    const float* b4    = (const float*)d_in[8];
    const float* Wfc   = (const float*)d_in[9];
    const float* bfc   = (const float*)d_in[10];
    const float* noise = (const float*)d_in[11];
    float* out = (float*)d_out;

    int N = in_sizes[0] / 256;
    int E = in_sizes[1] / 2;
    const int* src = ei;
    const int* dst = ei + E;
    int nScanBlocks = (N + 1023) / 1024;

    // Workspace layout
    float* B = (float*)d_ws;                                        // [N*128] f32
    unsigned short* Abf = (unsigned short*)(B + (size_t)N * 128);   // [N*128] bf16
    unsigned short* Bbf = Abf + (size_t)N * 128;                    // [N*128] bf16
    unsigned short* wT  = Bbf + (size_t)N * 128;                    // [128*256] bf16
    unsigned short* w4T = wT + 128 * 256;                           // [64*128] bf16
    float* dis     = (float*)(w4T + 64 * 128);                      // [N]
    float* pooledH = dis + N;                                       // [512*128]
    float* pooledT = pooledH + 512 * 128;                           // [512*64]
    int*   degi    = (int*)(pooledT + 512 * 64);                    // [N]
    int*   offs    = degi + N;                                      // [N+1]
    int*   cursor  = offs + N + 1;                                  // [N]
    int*   bsum    = cursor + N;                                    // [256]
    int*   adj     = bsum + 256;                                    // [E]

    hipMemsetAsync(degi, 0, (size_t)N * sizeof(int), stream);
    hipMemsetAsync(pooledT, 0, (size_t)(512 * 64) * sizeof(float), stream);

    // CSR build + one-time transposes
    deg_kernel<<<(E + 255) / 256, 256, 0, stream>>>(dst, degi, E);
    scan1_kernel<<<nScanBlocks, 256, 0, stream>>>(degi, bsum, N);
    scan2_kernel<<<1, 256, 0, stream>>>(bsum, nScanBlocks);
    scan3_kernel<<<nScanBlocks, 256, 0, stream>>>(degi, bsum, offs, cursor, dis, N, E);
    fill_kernel<<<(E + 255) / 256, 256, 0, stream>>>(src, dst, cursor, adj, E);
    wt_kernel<<<128, 256, 0, stream>>>(W1, wT);
    wt4_kernel<<<32, 256, 0, stream>>>(W4, w4T);

    // Layer 1 GEMM (MFMA)
    gemm1_mfma<<<(N + 63) / 64, 256, 0, stream>>>(x, wT, dis, Abf, B, N);

    // gather1 + fused relu/bias/rescale
    gather_kernel<1><<<(N + 15) / 16, 256, 0, stream>>>(offs, adj, dis, b1, Abf, Abf, B, Bbf, N);

    // gather2: B = hagg (f32), Bbf = bf16(hagg)
    gather_kernel<0><<<(N + 15) / 16, 256, 0, stream>>>(offs, adj, dis, b1, Abf, Abf, B, Bbf, N);

    // pooled T (MFMA) + pooled H (coalesced)
    pool2_mfma<<<(N + 63) / 64, 256, 0, stream>>>(Bbf, w4T, b4, noise, batch, pooledT, N);
    poolH_kernel<<<512, 128, 0, stream>>>(B, batch, pooledH, N);

    final_kernel<<<512, 64, 0, stream>>>(pooledH, pooledT, batch, W3, b3, Wfc, bfc, out, N);
}